// Round 18
// baseline (556.979 us; speedup 1.0000x reference)
//
#include <hip/hip_runtime.h>
#include <hip/hip_bf16.h>

#define N_AG   4096
#define T_IN   8
#define PRELEN 12
#define EDIM   64
#define HDIM   128
#define KTOT   320    // E + H (sh) + H (h)
#define GDIM   512    // 4*H
#define KI     10     // KTOT / 32
#define LOSCALE 2048.0f

typedef _Float16 f16x8 __attribute__((ext_vector_type(8)));
typedef _Float16 f16x4 __attribute__((ext_vector_type(4)));
typedef float    f32x4 __attribute__((ext_vector_type(4)));

// ---------------- workspace layout (float units) ----------------
// hA     @ 0        (524288)   h double buffer (f32)
// hB     @ 524288   (524288)
// c      @ 1048576  (524288)   block-private -> single buffer
// lastA  @ 1572864  (8192)     last double buffer
// lastB  @ 1581056  (8192)
// bsum   @ 1589248  (512)
// posAll @ 1589760  (57344)
// WfH    @ 1647104  (81920 floats = 163840 f16)
// WfL    @ 1729024  (81920 floats = 163840 f16)
// h16A   @ 1810944  (262208 floats = 4097x128 f16, row 4096 = zeros)
// h16B   @ 2073152  (262208)

// ---------------- init (verified, unchanged) ----------------
__global__ __launch_bounds__(256) void init_kernel(
    const float* __restrict__ tracks,
    const float* __restrict__ Wih, const float* __restrict__ Whh,
    const float* __restrict__ bih, const float* __restrict__ bhh,
    float* __restrict__ hA, float* __restrict__ hB, float* __restrict__ c,
    float* __restrict__ lastA, float* __restrict__ lastB,
    _Float16* __restrict__ WfH, _Float16* __restrict__ WfL,
    float* __restrict__ bsum, float* __restrict__ posAll,
    float* __restrict__ h16Af, float* __restrict__ h16Bf,
    float* __restrict__ out)
{
    int idx = blockIdx.x * 256 + threadIdx.x;   // grid covers 524288
    hA[idx] = 0.f;
    hB[idx] = 0.f;
    c[idx]  = 0.f;
    if (idx < 262208) { h16Af[idx] = 0.f; h16Bf[idx] = 0.f; }  // incl. pad row
    if (idx < KTOT * GDIM) {                    // pack W into MFMA fragment order, split f16
        int g = idx / KTOT, k = idx - g * KTOT;
        float val = (k < 192) ? Wih[g * 192 + k] : Whh[g * 128 + (k - 192)];
        int nt = g >> 4, ki = k >> 5;
        int ln = (g & 15) | (((k >> 3) & 3) << 4);
        int e  = k & 7;
        size_t off = (size_t)((nt * KI + ki) * 64 + ln) * 8 + e;
        _Float16 hi = (_Float16)val;
        WfH[off] = hi;
        WfL[off] = (_Float16)((val - (float)hi) * LOSCALE);
    }
    if (idx < N_AG) {                           // last = tracks[:, 7]
        lastA[idx * 2 + 0] = tracks[idx * 16 + 14];
        lastA[idx * 2 + 1] = tracks[idx * 16 + 15];
        lastB[idx * 2 + 0] = 0.f;
        lastB[idx * 2 + 1] = 0.f;
    }
    if (idx < GDIM) bsum[idx] = bih[idx] + bhh[idx];
    if (idx < 16)  out[idx] = tracks[idx];      // out[0:8] = tracks[0]
    if (idx < 7 * N_AG) {                       // posAll[t][a] = tracks[a, t]
        int t = idx / N_AG, a = idx & (N_AG - 1);
        posAll[idx * 2 + 0] = tracks[a * 16 + t * 2 + 0];
        posAll[idx * 2 + 1] = tracks[a * 16 + t * 2 + 1];
    }
}

// ---------------- fused per-step kernel, 16 waves, mask-shared pool ----------------
// 256 blocks x 1024 thr. Block owns 16 agents x ALL 512 gate cols.
// Pool: wave w ballots its 256-candidate window vs all 16 agents -> u64 masks
// in LDS (64 independent ballots, no serial cnt chain, 16x less LDS read);
// then wave w compacts agent w's words and gathers 2 rows/instruction.
// GEMM: r17-verified K-split. h/h16/last double-buffered by step parity.
__global__ void __launch_bounds__(1024, 1) social_step(
    const float* __restrict__ pp,       // positions for pool+emb (posAll[t] or lastIn)
    const float* __restrict__ We, const float* __restrict__ be,
    const _Float16* __restrict__ WfH, const _Float16* __restrict__ WfL,
    const float* __restrict__ bsum,
    const float* __restrict__ hIn, float* __restrict__ hOut,
    const _Float16* __restrict__ h16In, _Float16* __restrict__ h16Out,
    float* __restrict__ c,
    const float* __restrict__ lastIn, float* __restrict__ lastOut,
    const float* __restrict__ Wd, const float* __restrict__ bd,
    float* __restrict__ out,
    int firstStep, int decStep)
{
    __shared__ __align__(16) char smraw[86272];
    _Float16 (*AH)[64][8] = (_Float16(*)[64][8])smraw;              // 10 KB [KI][64][8]
    _Float16 (*AL)[64][8] = (_Float16(*)[64][8])(smraw + 10240);    // 10 KB
    float (*shs)[HDIM]    = (float(*)[HDIM])(smraw + 20480);        //  8 KB [16][128]
    unsigned short (*sidx)[512] = (unsigned short(*)[512])(smraw + 28672); // 16 KB [16][512]
    float (*hs)[HDIM]     = (float(*)[HDIM])(smraw + 28672);        //  8 KB (aliases sidx)
    float* posl           = (float*)(smraw + 45056);                // 32 KB [4096][2]
    float* accx           = (float*)(smraw + 45056);                // 32 KB (aliases posl)
    unsigned long long* masksL = (unsigned long long*)(smraw + 77824); // 8.25 KB [16][66]

    int tid  = threadIdx.x;
    int lane = tid & 63;
    int wv   = tid >> 6;                 // 0..15
    int a0   = blockIdx.x * 16;

    // ---- stage positions to LDS (pool) ----
    if (!firstStep) {
#pragma unroll
        for (int k = 0; k < 2; k++) {
            int u = tid + k * 1024;
            *(f32x4*)&posl[u * 4] = *(const f32x4*)(pp + (size_t)u * 4);
        }
    }

    // ---- stage emb + h fragments early (L2 latency hides under pool) ----
    for (int u = tid; u < 16 * 24; u += 1024) {   // 384 units: kg in {0..7, 24..39}
        int a = u & 15, v_ = u >> 4;
        int kg = (v_ < 8) ? v_ : v_ + 16;
        int ga = a0 + a;
        int k0 = kg * 8;
        float v[8];
        if (k0 < EDIM) {
            float px = pp[ga * 2], py = pp[ga * 2 + 1];
#pragma unroll
            for (int j = 0; j < 8; j++) {
                int k = k0 + j;
                v[j] = fmaf(px, We[k * 2], fmaf(py, We[k * 2 + 1], be[k]));
            }
        } else {
#pragma unroll
            for (int j = 0; j < 8; j++)
                v[j] = hIn[(unsigned)ga * HDIM + (k0 - EDIM - HDIM + j)];
        }
        f16x8 hi8, lo8;
#pragma unroll
        for (int j = 0; j < 8; j++) {
            _Float16 hv = (_Float16)v[j];
            hi8[j] = hv;
            lo8[j] = (_Float16)((v[j] - (float)hv) * LOSCALE);
        }
        int ki = kg >> 2, ln = a | ((kg & 3) << 4);
        *(f16x8*)&AH[ki][ln][0] = hi8;
        *(f16x8*)&AL[ki][ln][0] = lo8;
    }
    __syncthreads();      // posl ready

    if (!firstStep) {
        // ---- mask build: wave wv tests candidates [wv*256, wv*256+256) vs 16 agents ----
        const float2* pvl = (const float2*)posl;
#pragma unroll
        for (int s = 0; s < 4; s++) {
            int cand = wv * 256 + s * 64 + lane;
            float2 pj = pvl[cand];
            unsigned long long mkw = 0;
#pragma unroll
            for (int a = 0; a < 16; a++) {
                float2 pa = pvl[a0 + a];          // LDS broadcast
                float dx = pj.x - pa.x, dy = pj.y - pa.y;
                unsigned long long m = __ballot(dx * dx + dy * dy < 25.0f);
                if (lane == a) mkw = m;
            }
            if (lane < 16) masksL[lane * 66 + wv * 4 + s] = mkw;
        }
        __syncthreads();  // masks ready

        // ---- compact agent wv's 64 words -> sidx, then gather 2 rows/inst ----
        unsigned long long myw = masksL[wv * 66 + lane];
        unsigned long long ltmask = (1ull << lane) - 1ull;
        int cnt = 0;
#pragma unroll 8
        for (int k = 0; k < 64; k++) {
            unsigned long long wk = __shfl(myw, k);
            if ((wk >> lane) & 1ull) {
                int s = cnt + __popcll(wk & ltmask);
                if (s < 512) sidx[wv][s] = (unsigned short)(k * 64 + lane);
            }
            cnt += __popcll(wk);
        }
        if (cnt > 512) cnt = 512;
        int cpad = (cnt + 31) & ~31;
        if (cpad > 512) cpad = 512;
        if (lane < cpad - cnt) sidx[wv][cnt + lane] = (unsigned short)N_AG;

        int rhalf = lane >> 5;           // 0/1: which row of each pair
        int dq    = (lane & 31) * 4;     // dim quad
        float s0 = 0.f, s1 = 0.f, s2 = 0.f, s3 = 0.f;
        for (int t2 = 0; t2 < cpad; t2 += 32) {   // 32 rows in flight
            f16x4 v[16];
#pragma unroll
            for (int u = 0; u < 16; u++) {
                int j = sidx[wv][t2 + 2 * u + rhalf];
                v[u] = *(const f16x4*)(h16In + (size_t)j * HDIM + dq);
            }
#pragma unroll
            for (int u = 0; u < 16; u++) {
                s0 += (float)v[u][0]; s1 += (float)v[u][1];
                s2 += (float)v[u][2]; s3 += (float)v[u][3];
            }
        }
        s0 += __shfl_xor(s0, 32);
        s1 += __shfl_xor(s1, 32);
        s2 += __shfl_xor(s2, 32);
        s3 += __shfl_xor(s3, 32);
        if (rhalf == 0) {
            f32x4 r; r[0] = s0; r[1] = s1; r[2] = s2; r[3] = s3;
            *(f32x4*)&shs[wv][dq] = r;
        }
    }
    __syncthreads();      // shs ready

    // ---- stage sh fragments: kg in [8, 24) ----
    for (int u = tid; u < 16 * 16; u += 1024) {   // 256 units
        int a = u & 15, kg = 8 + (u >> 4);
        int k0 = kg * 8;
        float v[8];
#pragma unroll
        for (int j = 0; j < 8; j++)
            v[j] = firstStep ? 0.f : shs[a][k0 - EDIM + j];
        f16x8 hi8, lo8;
#pragma unroll
        for (int j = 0; j < 8; j++) {
            _Float16 hv = (_Float16)v[j];
            hi8[j] = hv;
            lo8[j] = (_Float16)((v[j] - (float)hv) * LOSCALE);
        }
        int ki = kg >> 2, ln = a | ((kg & 3) << 4);
        *(f16x8*)&AH[ki][ln][0] = hi8;
        *(f16x8*)&AL[ki][ln][0] = lo8;
    }
    __syncthreads();      // AH/AL complete

    // ---- MFMA gates GEMM, K-split across wave halves (r17 verified) ----
    int q    = wv & 7;
    int half = wv >> 3;
    int dcol = q * 16 + (lane & 15);
    const float inv = 1.0f / LOSCALE;

    f32x4 acc[4], accL[4];
#pragma unroll
    for (int g = 0; g < 4; g++) {
        float bb = half ? 0.f : bsum[dcol + g * 128];
        f32x4 z; z[0] = bb; z[1] = bb; z[2] = bb; z[3] = bb;
        acc[g] = z;
        f32x4 zz; zz[0] = 0.f; zz[1] = 0.f; zz[2] = 0.f; zz[3] = 0.f;
        accL[g] = zz;
    }
#pragma unroll
    for (int kk = 0; kk < 5; kk++) {
        int ki = half * 5 + kk;
        f16x8 ah = *(const f16x8*)&AH[ki][lane][0];
        f16x8 al = *(const f16x8*)&AL[ki][lane][0];
#pragma unroll
        for (int g = 0; g < 4; g++) {
            int nt = q + 8 * g;
            size_t off = (size_t)((nt * KI + ki) * 64 + lane) * 8;
            f16x8 bh = *(const f16x8*)&WfH[off];
            f16x8 bl = *(const f16x8*)&WfL[off];
            acc[g]  = __builtin_amdgcn_mfma_f32_16x16x32_f16(ah, bh, acc[g],  0, 0, 0);
            accL[g] = __builtin_amdgcn_mfma_f32_16x16x32_f16(al, bh, accL[g], 0, 0, 0);
            accL[g] = __builtin_amdgcn_mfma_f32_16x16x32_f16(ah, bl, accL[g], 0, 0, 0);
        }
    }
#pragma unroll
    for (int g = 0; g < 4; g++) {
#pragma unroll
        for (int r = 0; r < 4; r++)
            acc[g][r] = fmaf(accL[g][r], inv, acc[g][r]);
    }
    if (half) {
#pragma unroll
        for (int g = 0; g < 4; g++)
            *(f32x4*)&accx[(size_t)((q * 4 + g) * 64 + lane) * 4] = acc[g];
    }
    __syncthreads();

    // ---- half=0 combines + LSTM pointwise update in registers ----
    if (!half) {
#pragma unroll
        for (int g = 0; g < 4; g++) {
            f32x4 o = *(const f32x4*)&accx[(size_t)((q * 4 + g) * 64 + lane) * 4];
#pragma unroll
            for (int r = 0; r < 4; r++) acc[g][r] += o[r];
        }
#pragma unroll
        for (int r = 0; r < 4; r++) {
            int alc = (lane >> 4) * 4 + r;      // C/D row mapping
            int ga  = a0 + alc;
            float vi = acc[0][r], vf = acc[1][r], vg = acc[2][r], vo = acc[3][r];
            float ig = 1.f / (1.f + expf(-vi));
            float fg = 1.f / (1.f + expf(-vf));
            float gg = tanhf(vg);
            float og = 1.f / (1.f + expf(-vo));
            float cold = c[(unsigned)ga * HDIM + dcol];
            float cn = fmaf(fg, cold, ig * gg);
            float hn = og * tanhf(cn);
            c[(unsigned)ga * HDIM + dcol]      = cn;
            hOut[(unsigned)ga * HDIM + dcol]   = hn;
            h16Out[(unsigned)ga * HDIM + dcol] = (_Float16)hn;
            hs[alc][dcol] = hn;                 // for fused decode (aliases sidx)
        }
    }

    // ---- fused decoder tail: delta = h_new@Wd^T + bd; lastOut = lastIn + delta ----
    if (decStep >= 0) {
        __syncthreads();
        if (tid < 512) {
            int ag = tid >> 5, comp = (tid >> 4) & 1, l16 = tid & 15;
            float s = 0.f;
#pragma unroll
            for (int j = 0; j < 8; j++) {
                int d = l16 * 8 + j;
                s += hs[ag][d] * Wd[comp * HDIM + d];
            }
            s += __shfl_down(s, 8, 16);
            s += __shfl_down(s, 4, 16);
            s += __shfl_down(s, 2, 16);
            s += __shfl_down(s, 1, 16);
            if (l16 == 0) {
                int ga = a0 + ag;
                float nl = lastIn[ga * 2 + comp] + s + bd[comp];
                lastOut[ga * 2 + comp] = nl;
                if (ga == 0) out[(8 + decStep) * 2 + comp] = nl;
            }
        }
    }
}

extern "C" void kernel_launch(void* const* d_in, const int* in_sizes, int n_in,
                              void* d_out, int out_size, void* d_ws, size_t ws_size,
                              hipStream_t stream)
{
    const float* tracks = (const float*)d_in[0];
    const float* We     = (const float*)d_in[1];
    const float* be     = (const float*)d_in[2];
    const float* Wih    = (const float*)d_in[3];
    const float* Whh    = (const float*)d_in[4];
    const float* bih    = (const float*)d_in[5];
    const float* bhh    = (const float*)d_in[6];
    const float* Wd     = (const float*)d_in[7];
    const float* bd     = (const float*)d_in[8];
    float* out = (float*)d_out;
    float* ws  = (float*)d_ws;

    float*     hA     = ws;
    float*     hB     = ws + 524288;
    float*     c      = ws + 1048576;
    float*     lastA  = ws + 1572864;
    float*     lastB  = ws + 1581056;
    float*     bsum   = ws + 1589248;
    float*     posAll = ws + 1589760;
    _Float16*  WfH    = (_Float16*)(ws + 1647104);
    _Float16*  WfL    = (_Float16*)(ws + 1729024);
    float*     h16Af  = ws + 1810944;
    float*     h16Bf  = ws + 2073152;

    float*    hbuf[2]   = { hA, hB };
    _Float16* h16buf[2] = { (_Float16*)h16Af, (_Float16*)h16Bf };
    float*    lbuf[2]   = { lastA, lastB };

    init_kernel<<<2048, 256, 0, stream>>>(tracks, Wih, Whh, bih, bhh,
                                          hA, hB, c, lastA, lastB,
                                          WfH, WfL, bsum, posAll,
                                          h16Af, h16Bf, out);

    int k = 0;   // step counter: step k reads buf[(k+1)&1], writes buf[k&1]
    auto step = [&](const float* pp, const float* lin, float* lout,
                    int fs, int ds) {
        social_step<<<256, 1024, 0, stream>>>(
            pp, We, be, WfH, WfL, bsum,
            hbuf[(k + 1) & 1], hbuf[k & 1],
            h16buf[(k + 1) & 1], h16buf[k & 1],
            c, lin, lout, Wd, bd, out, fs, ds);
        k++;
    };

    // step 0: x0 = [emb(tracks[:,0]) | zeros], h=c=0
    step(posAll, nullptr, nullptr, 1, -1);

    // encoder: t = 0..6 (pool over posAll[t], emb(posAll[t]))
    for (int t = 0; t < T_IN - 1; t++)
        step(posAll + (size_t)t * N_AG * 2, nullptr, nullptr, 0, -1);

    // decoder: 12 steps (pool+emb over lastIn; decode writes lastOut)
    for (int s = 0; s < PRELEN; s++)
        step(lbuf[s & 1], lbuf[s & 1], lbuf[(s + 1) & 1], 0, s);
}